// Round 16
// baseline (362.837 us; speedup 1.0000x reference)
//
#include <hip/hip_runtime.h>
#include <math.h>

// B=4, T=48, W=8, H=8, C=32; d_ff=64; periods {2,3,4}. T%P==0 always.
// (1x1 + 3^4)/2 inception folded into one 81-tap conv (center tap 40).
// R16 = R15 with the period-dispatch bug fixed (stageA used Pv=per instead
// of Pv=per+2 -> wrong cidx<> template for every period). Structure: convs
// are per-CU global_load_lds delivery-bound (~19 KB/us/CU); grid = 256
// blocks (1/CU); weights staged ONCE per block; blocks own 1-2 bt-pair jobs
// (288 jobs), loop order chunk->job. Depth-1 barrier pipeline, R14 epilogues.

typedef __attribute__((ext_vector_type(8))) short bf16x8;
typedef __attribute__((ext_vector_type(4))) float f32x4;
typedef unsigned short u16;

// ---- workspace offsets (u16 units) ----
#define XC 3200                 // u16 per x cell (10*10*32)
#define HC 6400                 // u16 per h1 cell (10*10*64)
#define XSEG 617600             // 193 * XC   (cell 192 = zero cell)
#define ZSEG_END 636800         // + 3*6400 h1 zero cells
#define W1OFF 636800            // 165888 bf16: [tap 0..80][2048]
#define W2OFF 802688            // 165888 bf16: [tap 0..80][2048]
#define H1OFF 968576            // 3 periods x 193 cells x 6400
#define H1P 1235200             // per-period stride = 193*6400
#define PREP_N 1300352          // end of weight segment
#define OUT_Q 98304             // out-init float4 count
#define PREP_TOT (PREP_N + OUT_Q)

__device__ __forceinline__ u16 f2bf(float f) {
    unsigned u = __float_as_uint(f);
    unsigned r = u + 0x7fffu + ((u >> 16) & 1u);
    return (u16)(r >> 16);
}
__device__ __forceinline__ float gelu_exact(float v) {
    return 0.5f * v * (1.0f + erff(v * 0.7071067811865476f));
}

// async copy of 1 KB: 64 lanes x 16 B. LDS dest = wave-uniform base + lane*16.
__device__ __forceinline__ void cp1k(const u16* g, u16* l, int lane) {
    __builtin_amdgcn_global_load_lds(
        (const __attribute__((address_space(1))) unsigned int*)(g + lane * 8),
        (__attribute__((address_space(3))) unsigned int*)(l + lane * 8),
        16, 0, 0);
}

// ---- prep: x cells (swizzled) + h1 zero cells + weights + out = x ----
__global__ __launch_bounds__(256) void prep(
    const float* __restrict__ x,
    const float* __restrict__ w1_0, const float* __restrict__ w1_1,
    const float* __restrict__ w2_0, const float* __restrict__ w2_1,
    u16* __restrict__ ws, float* __restrict__ out) {
    int i = blockIdx.x * 256 + threadIdx.x;
    if (i < XSEG) {
        int cellidx = i / XC; int inner = i - cellidx * XC;
        int cellpos = inner >> 5; int low = inner & 31;
        int sc = low >> 3, jj = low & 7;
        int c = ((sc ^ (cellpos & 3)) << 3) + jj;
        int wp = cellpos / 10, hp = cellpos - (cellpos / 10) * 10;
        float v = 0.f;
        if (cellidx < 192 && wp >= 1 && wp <= 8 && hp >= 1 && hp <= 8)
            v = x[(cellidx * 64 + (wp - 1) * 8 + (hp - 1)) * 32 + c];
        ws[i] = f2bf(v);
    } else if (i < ZSEG_END) {
        int j = i - XSEG;
        int per = j / HC; int off = j - per * HC;
        ws[H1OFF + per * H1P + 192 * HC + off] = 0;
    } else if (i < ZSEG_END + 165888) {
        int j = i - W1OFF;
        int tap = j >> 11; int r = j & 2047;
        int chunk = r >> 3, jj = r & 7;
        int m = chunk & 15, nt = (chunk >> 4) & 3, quad = chunk >> 6;
        int o = nt * 16 + m, c = quad * 8 + jj;
        float v = 0.5f * w1_1[(o * 32 + c) * 81 + tap];
        if (tap == 40) v += 0.5f * w1_0[o * 32 + c];
        ws[i] = f2bf(v);
    } else if (i < PREP_N) {
        int j = i - W2OFF;
        int tap = j >> 11; int r = j & 2047;
        int chunk = r >> 3, jj = r & 7;
        int m = chunk & 15, nt = (chunk >> 4) & 1;
        int quad = (chunk >> 5) & 3, ks = chunk >> 7;
        int o = nt * 16 + m, c = ks * 32 + quad * 8 + jj;
        float v = 0.5f * w2_1[(o * 64 + c) * 81 + tap];
        if (tap == 40) v += 0.5f * w2_0[o * 64 + c];
        ws[i] = f2bf(v);
    } else if (i < PREP_TOT) {
        int j = i - PREP_N;
        ((float4*)out)[j] = ((const float4*)x)[j];
    }
}

// cell index for (b, l2, q2): valid -> b*48 + l2*P + q2, else zero cell 192
template<int P>
__device__ __forceinline__ int cidx(int bb, int l2, int q2) {
    constexpr int L = 48 / P;
    return ((unsigned)l2 < (unsigned)L && (unsigned)q2 < (unsigned)P)
               ? bb * 48 + l2 * P + q2 : 192;
}

// runtime-P dispatch: P = per+2 in {2,3,4}
__device__ __forceinline__ int cidx_rt(int P, int bb, int l2, int q2) {
    if (P == 2) return cidx<2>(bb, l2, q2);
    if (P == 3) return cidx<3>(bb, l2, q2);
    return cidx<4>(bb, l2, q2);
}

// block -> jobs: 256 blocks, 288 jobs (bt-pairs). gg = swizzled block id.
// gg < 224: 1 job (jid = gg); gg >= 224: 2 jobs (224 + 2*(gg-224), +1).
__device__ __forceinline__ void job_decode(int jid, int& per, int& bb, int& tp) {
    per = jid / 96; int rem = jid - per * 96;
    bb = rem / 24; tp = rem - bb * 24;
}

// ---- conv1 (C32->C64) + GELU. Block = 4 waves: (tloc, nh) = (wv>>1, wv&1).
// Weights staged once; chunk->job loop. ----
__global__ __launch_bounds__(256) void conv1_k(
    const u16* __restrict__ xs, const u16* __restrict__ w1b,
    u16* __restrict__ h1) {
    __shared__ __align__(16) u16 s_w[2 * 6144];      // 24 KB weight dbuf
    __shared__ __align__(16) u16 s_a[2 * 4 * 3584];  // 56 KB [job][cell][dbuf]
    int g = blockIdx.x;
    int gg = (g & 7) * 32 + (g >> 3);                // XCD-chunked
    int nj = (gg < 224) ? 1 : 2;
    int j0 = (gg < 224) ? gg : 224 + (gg - 224) * 2;

    int tid = threadIdx.x;
    int lane = tid & 63, wv = tid >> 6;
    int m = lane & 15, quad = lane >> 4;
    int tloc = wv >> 1, nh = wv & 1;

    int per[2], bb[2], tp[2], l0[2], q0[2], l1[2], q1[2];
    for (int jl = 0; jl < nj; ++jl) {
        job_decode(j0 + jl, per[jl], bb[jl], tp[jl]);
        int Pv = per[jl] + 2;
        int t0 = tp[jl] * 2, t1 = t0 + 1;
        l0[jl] = t0 / Pv; q0[jl] = t0 - l0[jl] * Pv;
        l1[jl] = t1 / Pv; q1[jl] = t1 - l1[jl] * Pv;
    }

    int sp[4];
#pragma unroll
    for (int mt = 0; mt < 4; ++mt) {
        int pos = mt * 16 + m;
        sp[mt] = (pos >> 3) * 10 + (pos & 7);
    }

    f32x4 acc[2][4][2];   // [job][mt][nt]
    for (int jl = 0; jl < 2; ++jl)
#pragma unroll
        for (int mt = 0; mt < 4; ++mt)
#pragma unroll
            for (int nt = 0; nt < 2; ++nt)
                acc[jl][mt][nt] = f32x4{0.f, 0.f, 0.f, 0.f};

    auto stageW = [&](int cgn) {
        const u16* src = w1b + (cgn * 3) * 2048;
        u16* dst = s_w + (cgn & 1) * 6144;
        int p0 = wv * 3;
#pragma unroll
        for (int i = 0; i < 3; ++i)
            cp1k(src + (p0 + i) * 512, dst + (p0 + i) * 512, lane);
    };
    // job jl, group gg2: 2 cells x 7 pieces, piece range [k0,k1)
    auto stageA = [&](int jl, int gg2, int k0, int k1) {
        int Pv = per[jl] + 2;   // FIXED (R15 bug: used per)
        int dl = gg2 / 3, dq = gg2 - (gg2 / 3) * 3;
        int c0 = cidx_rt(Pv, bb[jl], l0[jl] + dl - 1, q0[jl] + dq - 1);
        int c1 = cidx_rt(Pv, bb[jl], l1[jl] + dl - 1, q1[jl] + dq - 1);
        const u16* p0 = xs + c0 * XC;
        const u16* p1 = xs + c1 * XC;
        for (int k = k0 + wv; k < k1; k += 4) {
            int cell = k / 7, pc = k - (k / 7) * 7;
            cp1k((cell ? p1 : p0) + pc * 512,
                 s_a + ((jl * 2 + cell) * 2 + (gg2 & 1)) * 3584 + pc * 512, lane);
        }
    };

    stageW(0);
    for (int jl = 0; jl < nj; ++jl) stageA(jl, 0, 0, 14);

#pragma unroll 1
    for (int cg = 0; cg < 27; ++cg) {
        __syncthreads();
        if (cg < 26) stageW(cg + 1);
        int grp = cg / 3, part = cg - grp * 3;
        if (grp < 8)
            for (int jl = 0; jl < nj; ++jl)
                stageA(jl, grp + 1, part * 5, (part == 2) ? 14 : part * 5 + 5);

        const u16* bw = s_w + (cg & 1) * 6144;
        int dwb = part * 10;
        for (int jl = 0; jl < nj; ++jl) {
            const u16* ba = s_a + ((jl * 2 + tloc) * 2 + (grp & 1)) * 3584;
#pragma unroll
            for (int j = 0; j < 3; ++j) {
                const u16* tw = bw + j * 2048;
                bf16x8 wf[2];
#pragma unroll
                for (int nt = 0; nt < 2; ++nt)
                    wf[nt] = *(const bf16x8*)(tw +
                        (((quad * 4 + nh * 2 + nt) * 16 + m) << 3));
                bf16x8 af[4];
#pragma unroll
                for (int mt = 0; mt < 4; ++mt) {
                    int cellpos = sp[mt] + dwb + j;
                    af[mt] = *(const bf16x8*)(ba + cellpos * 32 +
                                              ((quad ^ (cellpos & 3)) << 3));
                }
#pragma unroll
                for (int mt = 0; mt < 4; ++mt)
#pragma unroll
                    for (int nt = 0; nt < 2; ++nt)
                        acc[jl][mt][nt] = __builtin_amdgcn_mfma_f32_16x16x32_bf16(
                            af[mt], wf[nt], acc[jl][mt][nt], 0, 0, 0);
            }
        }
    }

    // epilogue per job: GELU -> bf16 -> h1 cell interior + zero borders
    for (int jl = 0; jl < nj; ++jl) {
        int HB = per[jl] * H1P;
        int t = tp[jl] * 2 + tloc;
        u16* hcell = h1 + HB + (bb[jl] * 48 + t) * HC;
#pragma unroll
        for (int mt = 0; mt < 4; ++mt)
#pragma unroll
            for (int r = 0; r < 4; ++r) {
                int pos = mt * 16 + quad * 4 + r;
                int cellpos = ((pos >> 3) + 1) * 10 + (pos & 7) + 1;
#pragma unroll
                for (int nt = 0; nt < 2; ++nt) {
                    int o = nh * 32 + nt * 16 + m;
                    hcell[cellpos * 64 + (((o >> 3) ^ (cellpos & 7)) << 3) + (o & 7)] =
                        f2bf(gelu_exact(acc[jl][mt][nt][r]));
                }
            }
        unsigned int* h32 = (unsigned int*)hcell;
#pragma unroll
        for (int it = 0; it < 18; ++it) {
            int k = it * 64 + lane;
            int bp = k >> 5, u = k & 31;
            int cp;
            if (bp < 10) cp = bp;
            else if (bp < 20) cp = 90 + (bp - 10);
            else if (bp < 28) cp = (bp - 19) * 10;
            else cp = (bp - 27) * 10 + 9;
            h32[cp * 32 + u] = 0;
        }
    }
}

// ---- conv2 (C64->C32). Block = 4 waves: (tloc, mh). Weights once. ----
__global__ __launch_bounds__(256) void conv2_k(
    const u16* __restrict__ h1, const u16* __restrict__ w2b,
    float* __restrict__ out) {
    __shared__ __align__(16) u16 s_w[2 * 6144];      // 24 KB
    __shared__ __align__(16) u16 s_a[2 * 4 * 6656];  // 104 KB -> 128 KB total
    int g = blockIdx.x;
    int gg = (g & 7) * 32 + (g >> 3);
    int nj = (gg < 224) ? 1 : 2;
    int j0 = (gg < 224) ? gg : 224 + (gg - 224) * 2;

    int tid = threadIdx.x;
    int lane = tid & 63, wv = tid >> 6;
    int m = lane & 15, quad = lane >> 4;
    int tloc = wv >> 1, mh = wv & 1;

    int per[2], bb[2], tp[2], l0[2], q0[2], l1[2], q1[2];
    for (int jl = 0; jl < nj; ++jl) {
        job_decode(j0 + jl, per[jl], bb[jl], tp[jl]);
        int Pv = per[jl] + 2;
        int t0 = tp[jl] * 2, t1 = t0 + 1;
        l0[jl] = t0 / Pv; q0[jl] = t0 - l0[jl] * Pv;
        l1[jl] = t1 / Pv; q1[jl] = t1 - l1[jl] * Pv;
    }

    int sp[2];
#pragma unroll
    for (int mt = 0; mt < 2; ++mt) {
        int pos = mh * 32 + mt * 16 + m;
        sp[mt] = (pos >> 3) * 10 + (pos & 7);
    }

    f32x4 acc[2][2][2];   // [job][mt][nt]
    for (int jl = 0; jl < 2; ++jl)
#pragma unroll
        for (int mt = 0; mt < 2; ++mt)
#pragma unroll
            for (int nt = 0; nt < 2; ++nt)
                acc[jl][mt][nt] = f32x4{0.f, 0.f, 0.f, 0.f};

    auto stageW = [&](int cgn) {
        const u16* src = w2b + (cgn * 3) * 2048;
        u16* dst = s_w + (cgn & 1) * 6144;
        int p0 = wv * 3;
#pragma unroll
        for (int i = 0; i < 3; ++i)
            cp1k(src + (p0 + i) * 512, dst + (p0 + i) * 512, lane);
    };
    auto stageA = [&](int jl, int gg2, int k0, int k1) {
        int Pv = per[jl] + 2;   // FIXED (R15 bug: used per)
        int dl = gg2 / 3, dq = gg2 - (gg2 / 3) * 3;
        int c0 = cidx_rt(Pv, bb[jl], l0[jl] + dl - 1, q0[jl] + dq - 1);
        int c1 = cidx_rt(Pv, bb[jl], l1[jl] + dl - 1, q1[jl] + dq - 1);
        const u16* hb = h1 + per[jl] * H1P;
        const u16* p0 = hb + c0 * HC;
        const u16* p1 = hb + c1 * HC;
        for (int k = k0 + wv; k < k1; k += 4) {
            int cell = k / 13, pc = k - (k / 13) * 13;
            cp1k((cell ? p1 : p0) + pc * 512,
                 s_a + ((jl * 2 + cell) * 2 + (gg2 & 1)) * 6656 + pc * 512, lane);
        }
    };

    stageW(0);
    for (int jl = 0; jl < nj; ++jl) stageA(jl, 0, 0, 26);

#pragma unroll 1
    for (int cg = 0; cg < 27; ++cg) {
        __syncthreads();
        if (cg < 26) stageW(cg + 1);
        int grp = cg / 3, part = cg - grp * 3;
        if (grp < 8)
            for (int jl = 0; jl < nj; ++jl)
                stageA(jl, grp + 1, part * 9, (part == 2) ? 26 : part * 9 + 9);

        const u16* bw = s_w + (cg & 1) * 6144;
        int dwb = part * 10;
        for (int jl = 0; jl < nj; ++jl) {
            const u16* ba = s_a + ((jl * 2 + tloc) * 2 + (grp & 1)) * 6656;
#pragma unroll
            for (int j = 0; j < 3; ++j) {
                const u16* tw = bw + j * 2048;
                bf16x8 wf[2][2];   // [nt][ks]
#pragma unroll
                for (int nt = 0; nt < 2; ++nt)
#pragma unroll
                    for (int ks = 0; ks < 2; ++ks)
                        wf[nt][ks] = *(const bf16x8*)(tw +
                            ((((ks * 4 + quad) * 2 + nt) * 16 + m) << 3));
                bf16x8 af[2][2];   // [mt][ks]
#pragma unroll
                for (int mt = 0; mt < 2; ++mt) {
                    int cellpos = sp[mt] + dwb + j;
#pragma unroll
                    for (int ks = 0; ks < 2; ++ks)
                        af[mt][ks] = *(const bf16x8*)(ba + cellpos * 64 +
                            (((ks * 4 + quad) ^ (cellpos & 7)) << 3));
                }
#pragma unroll
                for (int mt = 0; mt < 2; ++mt)
#pragma unroll
                    for (int ks = 0; ks < 2; ++ks)
#pragma unroll
                        for (int nt = 0; nt < 2; ++nt)
                            acc[jl][mt][nt] = __builtin_amdgcn_mfma_f32_16x16x32_bf16(
                                af[mt][ks], wf[nt][ks], acc[jl][mt][nt], 0, 0, 0);
            }
        }
    }

    // epilogue per job: out += acc/3 (out pre-filled with x)
    const float s = 1.0f / 3.0f;
    for (int jl = 0; jl < nj; ++jl) {
        int t = tp[jl] * 2 + tloc;
        float* orow = out + (bb[jl] * 48 + t) * 2048;
#pragma unroll
        for (int mt = 0; mt < 2; ++mt)
#pragma unroll
            for (int nt = 0; nt < 2; ++nt)
#pragma unroll
                for (int r = 0; r < 4; ++r) {
                    int pos = mh * 32 + mt * 16 + quad * 4 + r;
                    atomicAdd(&orow[pos * 32 + nt * 16 + m],
                              acc[jl][mt][nt][r] * s);
                }
    }
}

extern "C" void kernel_launch(void* const* d_in, const int* in_sizes, int n_in,
                              void* d_out, int out_size, void* d_ws, size_t ws_size,
                              hipStream_t stream) {
    const float* x    = (const float*)d_in[0];
    const float* w1_0 = (const float*)d_in[1];
    const float* w1_1 = (const float*)d_in[2];
    const float* w2_0 = (const float*)d_in[3];
    const float* w2_1 = (const float*)d_in[4];
    float* out = (float*)d_out;

    u16* ws = (u16*)d_ws;
    u16* ws_x  = ws;
    u16* ws_w1 = ws + W1OFF;
    u16* ws_w2 = ws + W2OFF;
    u16* ws_h1 = ws + H1OFF;

    prep<<<(PREP_TOT + 255) / 256, 256, 0, stream>>>(
        x, w1_0, w1_1, w2_0, w2_1, ws, out);
    conv1_k<<<256, 256, 0, stream>>>(ws_x, ws_w1, ws_h1);
    conv2_k<<<256, 256, 0, stream>>>(ws_h1, ws_w2, out);
}

// Round 17
// 135.460 us; speedup vs baseline: 2.6786x; 2.6786x over previous
//
#include <hip/hip_runtime.h>
#include <math.h>

// B=4, T=48, W=8, H=8, C=32; d_ff=64; periods {2,3,4}. T%P==0 always.
// (1x1 + 3^4)/2 inception folded into one 81-tap conv (center tap 40).
// R17 = best-of assembly: R13 conv1 (52 KB LDS -> 3 blk/CU, depth-1
// barrier pipeline, 2-deep weight ring) + R14 conv2 + R14 fused epilogues
// (prep writes out=x; conv2 atomicAdds acc/3; no final_add, no memset).
// R16 lesson: no runtime-bounded job loops (scratch-spills accumulators).

typedef __attribute__((ext_vector_type(8))) short bf16x8;
typedef __attribute__((ext_vector_type(4))) float f32x4;
typedef unsigned short u16;

// ---- workspace offsets (u16 units) ----
#define XC 3200                 // u16 per x cell (10*10*32)
#define HC 6400                 // u16 per h1 cell (10*10*64)
#define XSEG 617600             // 193 * XC   (cell 192 = zero cell)
#define ZSEG_END 636800         // + 3*6400 h1 zero cells
#define W1OFF 636800            // 165888 bf16: [tap 0..80][2048]
#define W2OFF 802688            // 165888 bf16: [tap 0..80][2048]
#define H1OFF 968576            // 3 periods x 193 cells x 6400
#define H1P 1235200             // per-period stride = 193*6400
#define PREP_N 1300352          // end of weight segment
#define OUT_Q 98304             // out-init float4 count
#define PREP_TOT (PREP_N + OUT_Q)

__device__ __forceinline__ u16 f2bf(float f) {
    unsigned u = __float_as_uint(f);
    unsigned r = u + 0x7fffu + ((u >> 16) & 1u);
    return (u16)(r >> 16);
}
__device__ __forceinline__ float gelu_exact(float v) {
    return 0.5f * v * (1.0f + erff(v * 0.7071067811865476f));
}

// async copy of 1 KB: 64 lanes x 16 B. LDS dest = wave-uniform base + lane*16.
__device__ __forceinline__ void cp1k(const u16* g, u16* l, int lane) {
    __builtin_amdgcn_global_load_lds(
        (const __attribute__((address_space(1))) unsigned int*)(g + lane * 8),
        (__attribute__((address_space(3))) unsigned int*)(l + lane * 8),
        16, 0, 0);
}

// ---- prep: x cells (swizzled) + h1 zero cells + weights + out = x ----
__global__ __launch_bounds__(256) void prep(
    const float* __restrict__ x,
    const float* __restrict__ w1_0, const float* __restrict__ w1_1,
    const float* __restrict__ w2_0, const float* __restrict__ w2_1,
    u16* __restrict__ ws, float* __restrict__ out) {
    int i = blockIdx.x * 256 + threadIdx.x;
    if (i < XSEG) {
        int cellidx = i / XC; int inner = i - cellidx * XC;
        int cellpos = inner >> 5; int low = inner & 31;
        int sc = low >> 3, jj = low & 7;
        int c = ((sc ^ (cellpos & 3)) << 3) + jj;
        int wp = cellpos / 10, hp = cellpos - (cellpos / 10) * 10;
        float v = 0.f;
        if (cellidx < 192 && wp >= 1 && wp <= 8 && hp >= 1 && hp <= 8)
            v = x[(cellidx * 64 + (wp - 1) * 8 + (hp - 1)) * 32 + c];
        ws[i] = f2bf(v);
    } else if (i < ZSEG_END) {
        int j = i - XSEG;
        int per = j / HC; int off = j - per * HC;
        ws[H1OFF + per * H1P + 192 * HC + off] = 0;
    } else if (i < ZSEG_END + 165888) {
        int j = i - W1OFF;
        int tap = j >> 11; int r = j & 2047;
        int chunk = r >> 3, jj = r & 7;
        int m = chunk & 15, nt = (chunk >> 4) & 3, quad = chunk >> 6;
        int o = nt * 16 + m, c = quad * 8 + jj;
        float v = 0.5f * w1_1[(o * 32 + c) * 81 + tap];
        if (tap == 40) v += 0.5f * w1_0[o * 32 + c];
        ws[i] = f2bf(v);
    } else if (i < PREP_N) {
        int j = i - W2OFF;
        int tap = j >> 11; int r = j & 2047;
        int chunk = r >> 3, jj = r & 7;
        int m = chunk & 15, nt = (chunk >> 4) & 1;
        int quad = (chunk >> 5) & 3, ks = chunk >> 7;
        int o = nt * 16 + m, c = ks * 32 + quad * 8 + jj;
        float v = 0.5f * w2_1[(o * 64 + c) * 81 + tap];
        if (tap == 40) v += 0.5f * w2_0[o * 64 + c];
        ws[i] = f2bf(v);
    } else if (i < PREP_TOT) {
        int j = i - PREP_N;
        ((float4*)out)[j] = ((const float4*)x)[j];
    }
}

// cell index for (b, l2, q2): valid -> b*48 + l2*P + q2, else zero cell 192
template<int P>
__device__ __forceinline__ int cidx(int bb, int l2, int q2) {
    constexpr int L = 48 / P;
    return ((unsigned)l2 < (unsigned)L && (unsigned)q2 < (unsigned)P)
               ? bb * 48 + l2 * P + q2 : 192;
}

// ---- conv1 (C32->C64) + GELU. Block = 4 waves: (tloc, nh) = (wv>>1, wv&1).
// Wave: M=64 (its t), N=32 (its o-half). Depth-1 barrier pipeline. ----
template<int P>
__device__ __forceinline__ void conv1_body(
    const u16* __restrict__ xs, const u16* __restrict__ w1b,
    u16* __restrict__ h1, int tp, int bb,
    u16* __restrict__ s_w, u16* __restrict__ s_a) {
    constexpr int HB = (P == 2) ? 0 : (P == 3) ? H1P : 2 * H1P;

    int tid = threadIdx.x;
    int lane = tid & 63, wv = tid >> 6;
    int m = lane & 15, quad = lane >> 4;
    int tloc = wv >> 1, nh = wv & 1;

    int t0 = tp * 2, t1 = tp * 2 + 1;
    int l0 = t0 / P, q0 = t0 - l0 * P;
    int l1 = t1 / P, q1 = t1 - l1 * P;

    int sp[4];
#pragma unroll
    for (int mt = 0; mt < 4; ++mt) {
        int pos = mt * 16 + m;
        sp[mt] = (pos >> 3) * 10 + (pos & 7);
    }

    f32x4 acc[4][2];
#pragma unroll
    for (int mt = 0; mt < 4; ++mt)
#pragma unroll
        for (int nt = 0; nt < 2; ++nt) acc[mt][nt] = f32x4{0.f, 0.f, 0.f, 0.f};

    // weights chunk cgn = taps 3cgn..3cgn+2 (12 pieces): 3/wave
    auto stageW = [&](int cgn) {
        const u16* src = w1b + (cgn * 3) * 2048;
        u16* dst = s_w + (cgn & 1) * 6144;
        int p0 = wv * 3;
#pragma unroll
        for (int i = 0; i < 3; ++i)
            cp1k(src + (p0 + i) * 512, dst + (p0 + i) * 512, lane);
    };
    // act group gg: 2 cells x 7 pieces = 14, split across 3 chunks
    auto stageA = [&](int gg, int k0, int k1) {
        int dl = gg / 3, dq = gg - (gg / 3) * 3;
        const u16* c0 = xs + cidx<P>(bb, l0 + dl - 1, q0 + dq - 1) * XC;
        const u16* c1 = xs + cidx<P>(bb, l1 + dl - 1, q1 + dq - 1) * XC;
        for (int k = k0 + wv; k < k1; k += 4) {
            int cell = k / 7, pc = k - (k / 7) * 7;
            cp1k((cell ? c1 : c0) + pc * 512,
                 s_a + (cell * 2 + (gg & 1)) * 3584 + pc * 512, lane);
        }
    };

    stageW(0);
    stageA(0, 0, 14);

#pragma unroll 1
    for (int cg = 0; cg < 27; ++cg) {
        __syncthreads();   // implicit vmcnt(0): chunk cg delivered; all waves
                           // done with cg-1 -> safe to overwrite its buffers
        if (cg < 26) stageW(cg + 1);
        int grp = cg / 3, part = cg - grp * 3;
        if (grp < 8) stageA(grp + 1, part * 5, (part == 2) ? 14 : part * 5 + 5);

        const u16* bw = s_w + (cg & 1) * 6144;
        const u16* ba = s_a + (tloc * 2 + (grp & 1)) * 3584;
        int dwb = part * 10;   // dw = part, dh = j
#pragma unroll
        for (int j = 0; j < 3; ++j) {
            const u16* tw = bw + j * 2048;
            bf16x8 wf[2];
#pragma unroll
            for (int nt = 0; nt < 2; ++nt)
                wf[nt] = *(const bf16x8*)(tw +
                    (((quad * 4 + nh * 2 + nt) * 16 + m) << 3));
            bf16x8 af[4];
#pragma unroll
            for (int mt = 0; mt < 4; ++mt) {
                int cellpos = sp[mt] + dwb + j;
                af[mt] = *(const bf16x8*)(ba + cellpos * 32 +
                                          ((quad ^ (cellpos & 3)) << 3));
            }
#pragma unroll
            for (int mt = 0; mt < 4; ++mt)
#pragma unroll
                for (int nt = 0; nt < 2; ++nt)
                    acc[mt][nt] = __builtin_amdgcn_mfma_f32_16x16x32_bf16(
                        af[mt], wf[nt], acc[mt][nt], 0, 0, 0);
        }
    }

    // epilogue: GELU -> bf16 -> swizzled h1 cell interior + zero borders
    int t = tp * 2 + tloc;
    u16* hcell = h1 + HB + (bb * 48 + t) * HC;
#pragma unroll
    for (int mt = 0; mt < 4; ++mt)
#pragma unroll
        for (int r = 0; r < 4; ++r) {
            int pos = mt * 16 + quad * 4 + r;
            int cellpos = ((pos >> 3) + 1) * 10 + (pos & 7) + 1;
#pragma unroll
            for (int nt = 0; nt < 2; ++nt) {
                int o = nh * 32 + nt * 16 + m;
                hcell[cellpos * 64 + (((o >> 3) ^ (cellpos & 7)) << 3) + (o & 7)] =
                    f2bf(gelu_exact(acc[mt][nt][r]));
            }
        }
    // zero the 36 border cellpos (both nh waves duplicate: benign zero race)
    unsigned int* h32 = (unsigned int*)hcell;
#pragma unroll
    for (int it = 0; it < 18; ++it) {
        int k = it * 64 + lane;
        int bp = k >> 5, u = k & 31;
        int cp;
        if (bp < 10) cp = bp;
        else if (bp < 20) cp = 90 + (bp - 10);
        else if (bp < 28) cp = (bp - 19) * 10;
        else cp = (bp - 27) * 10 + 9;
        h32[cp * 32 + u] = 0;
    }
}

__global__ __launch_bounds__(256) void conv1_k(
    const u16* __restrict__ ws_x, const u16* __restrict__ ws_w1,
    u16* __restrict__ ws_h1) {
    __shared__ __align__(16) u16 s_w[2 * 6144];   // 24 KB weight dbuf
    __shared__ __align__(16) u16 s_a[4 * 3584];   // 28 KB -> 52 KB, 3 blk/CU
    int g = blockIdx.x;
    int jid = (g & 7) * 36 + (g >> 3);            // XCD-chunked, 288 = 8*36
    int per = jid / 96; int rem = jid - per * 96;
    int bb = rem / 24; int tp = rem - bb * 24;
    if (per == 0)      conv1_body<2>(ws_x, ws_w1, ws_h1, tp, bb, s_w, s_a);
    else if (per == 1) conv1_body<3>(ws_x, ws_w1, ws_h1, tp, bb, s_w, s_a);
    else               conv1_body<4>(ws_x, ws_w1, ws_h1, tp, bb, s_w, s_a);
}

// ---- conv2 (C64->C32). Block = 4 waves: (tloc, mh) = (wv>>1, wv&1).
// Depth-1 pipeline; epilogue: atomicAdd acc/3 into out (pre-filled x). ----
template<int P>
__device__ __forceinline__ void conv2_body(
    const u16* __restrict__ h1, const u16* __restrict__ w2b,
    float* __restrict__ out, int tp, int bb,
    u16* __restrict__ s_w, u16* __restrict__ s_a) {
    constexpr int HB = (P == 2) ? 0 : (P == 3) ? H1P : 2 * H1P;

    int tid = threadIdx.x;
    int lane = tid & 63, wv = tid >> 6;
    int m = lane & 15, quad = lane >> 4;
    int tloc = wv >> 1, mh = wv & 1;

    int t0 = tp * 2, t1 = tp * 2 + 1;
    int l0 = t0 / P, q0 = t0 - l0 * P;
    int l1 = t1 / P, q1 = t1 - l1 * P;
    const u16* hb = h1 + HB;

    int sp[2];
#pragma unroll
    for (int mt = 0; mt < 2; ++mt) {
        int pos = mh * 32 + mt * 16 + m;
        sp[mt] = (pos >> 3) * 10 + (pos & 7);
    }

    f32x4 acc[2][2];
#pragma unroll
    for (int mt = 0; mt < 2; ++mt)
#pragma unroll
        for (int nt = 0; nt < 2; ++nt) acc[mt][nt] = f32x4{0.f, 0.f, 0.f, 0.f};

    auto stageW = [&](int cgn) {
        const u16* src = w2b + (cgn * 3) * 2048;
        u16* dst = s_w + (cgn & 1) * 6144;
        int p0 = wv * 3;
#pragma unroll
        for (int i = 0; i < 3; ++i)
            cp1k(src + (p0 + i) * 512, dst + (p0 + i) * 512, lane);
    };
    auto stageA = [&](int gg, int k0, int k1) {
        int dl = gg / 3, dq = gg - (gg / 3) * 3;
        const u16* c0 = hb + cidx<P>(bb, l0 + dl - 1, q0 + dq - 1) * HC;
        const u16* c1 = hb + cidx<P>(bb, l1 + dl - 1, q1 + dq - 1) * HC;
        for (int k = k0 + wv; k < k1; k += 4) {
            int cell = k / 13, pc = k - (k / 13) * 13;
            cp1k((cell ? c1 : c0) + pc * 512,
                 s_a + (cell * 2 + (gg & 1)) * 6656 + pc * 512, lane);
        }
    };

    stageW(0);
    stageA(0, 0, 26);

#pragma unroll 1
    for (int cg = 0; cg < 27; ++cg) {
        __syncthreads();
        if (cg < 26) stageW(cg + 1);
        int grp = cg / 3, part = cg - grp * 3;
        if (grp < 8) stageA(grp + 1, part * 9, (part == 2) ? 26 : part * 9 + 9);

        const u16* bw = s_w + (cg & 1) * 6144;
        const u16* ba = s_a + (tloc * 2 + (grp & 1)) * 6656;
        int dwb = part * 10;
#pragma unroll
        for (int j = 0; j < 3; ++j) {
            const u16* tw = bw + j * 2048;
            bf16x8 wf[2][2];   // [nt][ks]
#pragma unroll
            for (int nt = 0; nt < 2; ++nt)
#pragma unroll
                for (int ks = 0; ks < 2; ++ks)
                    wf[nt][ks] = *(const bf16x8*)(tw +
                        ((((ks * 4 + quad) * 2 + nt) * 16 + m) << 3));
            bf16x8 af[2][2];   // [mt][ks]
#pragma unroll
            for (int mt = 0; mt < 2; ++mt) {
                int cellpos = sp[mt] + dwb + j;
#pragma unroll
                for (int ks = 0; ks < 2; ++ks)
                    af[mt][ks] = *(const bf16x8*)(ba + cellpos * 64 +
                        (((ks * 4 + quad) ^ (cellpos & 7)) << 3));
            }
#pragma unroll
            for (int mt = 0; mt < 2; ++mt)
#pragma unroll
                for (int ks = 0; ks < 2; ++ks)
#pragma unroll
                    for (int nt = 0; nt < 2; ++nt)
                        acc[mt][nt] = __builtin_amdgcn_mfma_f32_16x16x32_bf16(
                            af[mt][ks], wf[nt][ks], acc[mt][nt], 0, 0, 0);
        }
    }

    // epilogue: out += acc/3 (softmax(ones) weights); out pre-filled with x
    int t = tp * 2 + tloc;
    float* orow = out + (bb * 48 + t) * 2048;
    const float s = 1.0f / 3.0f;
#pragma unroll
    for (int mt = 0; mt < 2; ++mt)
#pragma unroll
        for (int nt = 0; nt < 2; ++nt)
#pragma unroll
            for (int r = 0; r < 4; ++r) {
                int pos = mh * 32 + mt * 16 + quad * 4 + r;
                atomicAdd(&orow[pos * 32 + nt * 16 + m], acc[mt][nt][r] * s);
            }
}

__global__ __launch_bounds__(256) void conv2_k(
    const u16* __restrict__ ws_h1, const u16* __restrict__ ws_w2,
    float* __restrict__ out) {
    __shared__ __align__(16) u16 s_w[2 * 6144];   // 24 KB
    __shared__ __align__(16) u16 s_a[4 * 6656];   // 52 KB -> 76 KB total
    int g = blockIdx.x;
    int jid = (g & 7) * 36 + (g >> 3);            // same XCD mapping as conv1
    int per = jid / 96; int rem = jid - per * 96;
    int bb = rem / 24; int tp = rem - bb * 24;
    if (per == 0)      conv2_body<2>(ws_h1, ws_w2, out, tp, bb, s_w, s_a);
    else if (per == 1) conv2_body<3>(ws_h1, ws_w2, out, tp, bb, s_w, s_a);
    else               conv2_body<4>(ws_h1, ws_w2, out, tp, bb, s_w, s_a);
}

extern "C" void kernel_launch(void* const* d_in, const int* in_sizes, int n_in,
                              void* d_out, int out_size, void* d_ws, size_t ws_size,
                              hipStream_t stream) {
    const float* x    = (const float*)d_in[0];
    const float* w1_0 = (const float*)d_in[1];
    const float* w1_1 = (const float*)d_in[2];
    const float* w2_0 = (const float*)d_in[3];
    const float* w2_1 = (const float*)d_in[4];
    float* out = (float*)d_out;

    u16* ws = (u16*)d_ws;
    u16* ws_x  = ws;
    u16* ws_w1 = ws + W1OFF;
    u16* ws_w2 = ws + W2OFF;
    u16* ws_h1 = ws + H1OFF;

    prep<<<(PREP_TOT + 255) / 256, 256, 0, stream>>>(
        x, w1_0, w1_1, w2_0, w2_1, ws, out);
    conv1_k<<<288, 256, 0, stream>>>(ws_x, ws_w1, ws_h1);
    conv2_k<<<288, 256, 0, stream>>>(ws_h1, ws_w2, out);
}